// Round 7
// baseline (499.072 us; speedup 1.0000x reference)
//
#include <hip/hip_runtime.h>

// ---------------------------------------------------------------------------
// SlidingWindowSelfAttention on MI355X (gfx950), bf16 MFMA pipeline:
//   cast(x,wqkv,wout) -> GEMM1 qkv (Q scaled, V written transposed)
//   -> flash attention (S^T = K Q^T formulation) -> GEMM2 out (fp32)
// R10: GEMM keeps R9's 128B-granule swizzled staging (proven: 246->200us,
//     MfmaUtil 36.6->45.5) and replaces the per-tile __syncthreads vmcnt(0)
//     DRAIN with a counted-vmcnt cadence (T4, m218):
//       body g: stage(g+1); s_waitcnt vmcnt(8); s_barrier;   <- retires tile
//                ph1 kk0 reads+MFMA; ph2 kk1 reads+MFMA;        g only, g+1
//                s_barrier;                                     stays in
//     so the global->LDS queue NEVER empties in the loop.        flight
//     Write-safety: stage(g+1) overwrites tile g-1's slots; its readers
//     passed lgkmcnt(0) before the end-of-body barrier of g-1 (2 bars/tile).
//     Stage addressing hoisted to 4 base pointers (VALUBusy 21% -> target
//     ~15). attn unchanged from R7 (passed twice).
// ---------------------------------------------------------------------------

typedef __bf16 bf16x8 __attribute__((ext_vector_type(8)));
typedef float  f32x4  __attribute__((ext_vector_type(4)));
typedef unsigned short u16x4 __attribute__((ext_vector_type(4)));

#define MFMA(a, b, c) __builtin_amdgcn_mfma_f32_16x16x32_bf16(a, b, c, 0, 0, 0)

__device__ __forceinline__ unsigned short f2bf(float f) {
  union { float f; unsigned u; } v; v.f = f;
  unsigned r = v.u + 0x7FFFu + ((v.u >> 16) & 1u);   // RNE
  return (unsigned short)(r >> 16);
}

// async global->LDS, 16B/lane; LDS dest = wave-uniform base + lane*16
__device__ __forceinline__ void gl16(const void* g, void* l) {
  __builtin_amdgcn_global_load_lds(
      (const __attribute__((address_space(1))) unsigned int*)g,
      (__attribute__((address_space(3))) unsigned int*)l, 16, 0, 0);
}

// ---------------------------------------------------------------------------
__global__ void cast_bf16(const float4* __restrict__ in,
                          u16x4* __restrict__ out, int n4) {
  int i = blockIdx.x * blockDim.x + threadIdx.x;
  if (i < n4) {
    float4 v = in[i];
    u16x4 o;
    o[0] = f2bf(v.x); o[1] = f2bf(v.y); o[2] = f2bf(v.z); o[3] = f2bf(v.w);
    out[i] = o;
  }
}

// ---------------------------------------------------------------------------
// C = A * B^T. A:[M,K] bf16 row-major, B:[N,K] bf16 row-major (torch weight).
// 256x256 tile, BK=64, 8 waves each 128x64.
// LDS ring: 8 slots x 16KB = 2 tiles; tile g occupies half (g&1):
//   slot 0: A rows 0-127 | slot 1: A rows 128-255 | slot 2: B 0-127 | 3: B 128-255
// Stage unit = 8 rows x 128B (1KB, one gl16): lane (r=lane>>3, c=lane&7)
// loads global [base+r][16B-chunk (c^r)] -> LDS linear lane*16. ds_read uses
// chunk (m ^ (row&7)) to recover chunk m; row r of a 128-row quarter lives
// at byte (r>>3)*1024 + (r&7)*128 within its per-wave 2KB unit pair.
// 8-lane groups hit 8 distinct 4-bank groups -> conflict-free b128.
// Counted-vmcnt body (tile g):
//   stage(g+1)                  [into slots of g-1; safe: end-bar of g-1]
//   s_waitcnt vmcnt(8)          [retires tile g; g+1 stays in flight]
//   s_barrier                   [tile g LDS-visible to all waves]
//   ph1: ds_read kk0; lgkm0+schedbar; setprio(1) 32 MFMA setprio(0)
//   ph2: ds_read kk1; lgkm0+schedbar; setprio(1) 32 MFMA setprio(0)
//   s_barrier                   [all waves done reading tile g]
// MODE 1: qkv epilogue (Q scaled 1/sqrt(D), V transposed into VT[B,H,D,S]).
// MODE 2: fp32 row-major C.
template <int MODE>
__global__ __launch_bounds__(512, 2) void gemm_bt(
    const unsigned short* __restrict__ A, const unsigned short* __restrict__ Bw,
    void* __restrict__ C1, void* __restrict__ C2, int K, int Nstride) {
  __shared__ __align__(16) unsigned char sm[131072];  // 8 x 16KB quarter ring
  const int tid = threadIdx.x, lane = tid & 63, w = tid >> 6;   // 8 waves
  const int l15 = lane & 15, lg = lane >> 4;
  const int wr = w >> 2, wc = w & 3;          // wave tile: rows wr*128, cols wc*64

  // staging lane constants: 8 rows x 128B unit, source chunk pre-swizzled
  const int rr = lane >> 3;                   // row within unit (0..7)
  const int cs = (((lane & 7) ^ rr) << 3);    // swizzled src chunk (shorts)

  // ds_read lane constants: frag row l15, K-chunk m = kk*4+lg stored at
  // chunk (m ^ (l15&7)); row l15 at byte (l15>>3)*1024 + (l15&7)*128.
  const int r7 = l15 & 7;
  const int mc0 = (l15 >> 3) * 1024 + r7 * 128 + ((lg ^ r7) << 4);
  const int mc1 = (l15 >> 3) * 1024 + r7 * 128 + (((4 + lg) ^ r7) << 4);

  // XCD-bijective swizzle (gridDim.x % 8 == 0 for both GEMMs), M=8192 fixed.
  int id = (int)blockIdx.x;
  int cpx = (int)gridDim.x >> 3;
  int sid = (id & 7) * cpx + (id >> 3);
  const int bm = (sid & 31) * 256;            // nmt = 8192/256 = 32
  const int bn = (sid >> 5) * 256;

  f32x4 acc[8][4] = {};
  const int nt = K >> 6;                      // K-tiles of 64
  const size_t row8 = (size_t)8 * K;          // 8-row stride (shorts)

  // hoisted staging base pointers (per wave: rows w*16+rr .. +8 of each part)
  const unsigned short* pA0 = A  + (size_t)(bm +       w * 16 + rr) * K + cs;
  const unsigned short* pA1 = A  + (size_t)(bm + 128 + w * 16 + rr) * K + cs;
  const unsigned short* pB0 = Bw + (size_t)(bn +       w * 16 + rr) * K + cs;
  const unsigned short* pB1 = Bw + (size_t)(bn + 128 + w * 16 + rr) * K + cs;

  auto stage = [&](int t) {                   // one tile = 8 gl16/wave
    int kt = ((t < nt) ? t : nt - 1) << 6;    // clamp: dummy re-load at tail
    unsigned char* dst = sm + (t & 1) * 65536 + w * 2048;
    gl16(pA0 + kt, dst);           gl16(pA0 + kt + row8, dst + 1024);
    gl16(pA1 + kt, dst + 16384);   gl16(pA1 + kt + row8, dst + 17408);
    gl16(pB0 + kt, dst + 32768);   gl16(pB0 + kt + row8, dst + 33792);
    gl16(pB1 + kt, dst + 49152);   gl16(pB1 + kt + row8, dst + 50176);
  };

  // prologue: tile 0 in flight (8 loads/wave)
  stage(0);

  for (int g = 0; g < nt; ++g) {
    // stage next tile FIRST, then counted wait: retire tile g, keep g+1 in flight
    stage(g + 1);
    asm volatile("s_waitcnt vmcnt(8)" ::: "memory");
    __builtin_amdgcn_s_barrier();             // tile g visible block-wide
    __builtin_amdgcn_sched_barrier(0);

    const unsigned char* Abase = sm + (((g & 1) * 4 + wr) << 14);
    const unsigned char* Bbase =
        sm + (((g & 1) * 4 + 2 + (wc >> 1)) << 14) + ((wc & 1) << 13);
    bf16x8 af[8], bfr[4];

    // ---- ph1: kk=0 reads + MFMA ----
#pragma unroll
    for (int i = 0; i < 8; i++)
      af[i] = *(const bf16x8*)(Abase + i * 2048 + mc0);
#pragma unroll
    for (int j = 0; j < 4; j++)
      bfr[j] = *(const bf16x8*)(Bbase + j * 2048 + mc0);
    asm volatile("s_waitcnt lgkmcnt(0)" ::: "memory");
    __builtin_amdgcn_sched_barrier(0);
    __builtin_amdgcn_s_setprio(1);
#pragma unroll
    for (int i = 0; i < 8; i++)
#pragma unroll
      for (int j = 0; j < 4; j++)
        acc[i][j] = MFMA(af[i], bfr[j], acc[i][j]);
    __builtin_amdgcn_s_setprio(0);

    // ---- ph2: kk=1 reads + MFMA (overlaps ph1 MFMA execution) ----
#pragma unroll
    for (int i = 0; i < 8; i++)
      af[i] = *(const bf16x8*)(Abase + i * 2048 + mc1);
#pragma unroll
    for (int j = 0; j < 4; j++)
      bfr[j] = *(const bf16x8*)(Bbase + j * 2048 + mc1);
    asm volatile("s_waitcnt lgkmcnt(0)" ::: "memory");
    __builtin_amdgcn_sched_barrier(0);
    __builtin_amdgcn_s_setprio(1);
#pragma unroll
    for (int i = 0; i < 8; i++)
#pragma unroll
      for (int j = 0; j < 4; j++)
        acc[i][j] = MFMA(af[i], bfr[j], acc[i][j]);
    __builtin_amdgcn_s_setprio(0);

    // end-of-tile: all waves done reading tile g (its slots re-staged next body)
    __builtin_amdgcn_s_barrier();
  }

  // drain dummy tail stages before exit: next block on this CU owns the LDS
  asm volatile("s_waitcnt vmcnt(0)" ::: "memory");

  // C/D layout: col n = lane&15, row m = (lane>>4)*4 + r  [m89/m91 verified]
  if (MODE == 1) {
    unsigned short* QK = (unsigned short*)C1;  // [8192][4096] = Q|K
    unsigned short* VT = (unsigned short*)C2;  // [2*16*128][4096]
    if (bn < 4096) {
      const float scl = (bn < 2048) ? 0.08838834764831845f : 1.0f;  // Q pre-scale
#pragma unroll
      for (int mi = 0; mi < 8; mi++) {
        int m0 = bm + wr * 128 + mi * 16 + lg * 4;
#pragma unroll
        for (int j = 0; j < 4; j++) {
          int n = bn + wc * 64 + j * 16 + l15;
#pragma unroll
          for (int r = 0; r < 4; r++)
            QK[(size_t)(m0 + r) * 4096 + n] = f2bf(acc[mi][j][r] * scl);
        }
      }
    } else {  // V: 4 consecutive m = consecutive s in VT -> packed 8B store
#pragma unroll
      for (int mi = 0; mi < 8; mi++) {
        int m0 = bm + wr * 128 + mi * 16 + lg * 4;
        int bb = m0 >> 12, s = m0 & 4095;
#pragma unroll
        for (int j = 0; j < 4; j++) {
          int n4 = bn + wc * 64 + j * 16 + l15 - 4096;
          int hh = n4 >> 7, d = n4 & 127;
          u16x4 pk;
#pragma unroll
          for (int r = 0; r < 4; r++) pk[r] = f2bf(acc[mi][j][r]);
          *(u16x4*)(VT + ((size_t)((bb * 16 + hh) * 128 + d) * 4096 + s)) = pk;
        }
      }
    }
  } else {
    float* C = (float*)C1;
#pragma unroll
    for (int mi = 0; mi < 8; mi++) {
      int m0 = bm + wr * 128 + mi * 16 + lg * 4;
#pragma unroll
      for (int j = 0; j < 4; j++) {
        int n = bn + wc * 64 + j * 16 + l15;
#pragma unroll
        for (int r = 0; r < 4; r++)
          C[(size_t)(m0 + r) * Nstride + n] = acc[mi][j][r];
      }
    }
  }
}

// ---------------------------------------------------------------------------
// Flash attention, S^T = K·Q^T formulation. Block = (b,h,128 queries),
// 4 waves x 32 queries. KV tiles of 64, span [q0-512, q0+128).
// R7 pipeline (unchanged, passed twice): K double-buffered, V re-staged in
// place, two counted vmcnt(4) per tile. LDS 66KB -> 2 blocks/CU.
__global__ __launch_bounds__(256, 2) void attn(
    const unsigned short* __restrict__ QK,  // [B*S][4096], Q pre-scaled
    const unsigned short* __restrict__ VT,  // [B*H*D][S]
    unsigned short* __restrict__ O) {       // [B*S][2048]
  __shared__ unsigned char sm[67584];
  // [0,16K): Kbuf0  [16K,32K): Kbuf1  [32K,48K): V frags [db8][kvs2][lane]
  // [48K,66K): P^T per wave 4608B: [m 32][kv 64] bf16, row stride 144B
  const int tid = threadIdx.x, lane = tid & 63, w = tid >> 6;
  const int l15 = lane & 15, lg = lane >> 4;
  const int bid = blockIdx.x;
  const int sid = (bid & 7) * 128 + (bid >> 3);   // XCD-contiguous q-chunks
  const int qc = sid & 31, h = (sid >> 5) & 15, b = sid >> 9;
  const int q0 = qc * 128;

  // Q fragments (B-operand: lane&15 = query, lg*8 = d-chunk) direct to regs
  bf16x8 qf[2][4];
#pragma unroll
  for (int mb = 0; mb < 2; mb++) {
    const unsigned short* qrow =
        QK + (size_t)(b * 4096 + q0 + (2 * w + mb) * 16 + l15) * 4096 + h * 128 + lg * 8;
#pragma unroll
    for (int ks = 0; ks < 4; ks++) qf[mb][ks] = *(const bf16x8*)(qrow + ks * 32);
  }

  float mrun[2] = {-1e30f, -1e30f}, lrun[2] = {0.f, 0.f};
  f32x4 oacc[8][2] = {};  // O^T tiles [db][mb]: row=d, col=query

  const int t0 = (q0 < 512) ? (512 - q0) >> 6 : 0;  // skip kv<0 tiles
  unsigned char* Ps = sm + 49152 + w * 4608;

  // prologue: stage K(t0)->Kbuf[t0&1] and V(t0)->V, full drain once
  {
    const int kv0 = q0 - 512 + t0 * 64;
#pragma unroll
    for (int u = 0; u < 4; u++) {
      int f = w + u * 4;
      int kvb = f >> 2, ks = f & 3;
      gl16(QK + (size_t)(b * 4096 + kv0 + kvb * 16 + l15) * 4096 + 2048 + h * 128 + ks * 32 + lg * 8,
           sm + (t0 & 1) * 16384 + f * 1024);
      int db = f >> 1, kvs = f & 1;
      gl16(VT + (size_t)((b * 16 + h) * 128 + db * 16 + l15) * 4096 + kv0 + kvs * 32 + lg * 8,
           sm + 32768 + f * 1024);
    }
  }
  asm volatile("s_waitcnt vmcnt(0)" ::: "memory");
  __builtin_amdgcn_s_barrier();

  for (int t = t0; t < 10; t++) {
    const int kv0 = q0 - 512 + t * 64;
    const int X = t & 1;
    const int tn = (t + 1 < 10) ? t + 1 : 9;        // clamp: dummy tail stage
    const int kvn = q0 - 512 + tn * 64;

    // stage K(t+1) -> Kbuf[X^1] (region's last readers synced 2 bars ago)
#pragma unroll
    for (int u = 0; u < 4; u++) {
      int f = w + u * 4;
      int kvb = f >> 2, ks = f & 3;
      gl16(QK + (size_t)(b * 4096 + kvn + kvb * 16 + l15) * 4096 + 2048 + h * 128 + ks * 32 + lg * 8,
           sm + (X ^ 1) * 16384 + f * 1024);
    }

    // S^T tiles [kvb][mb]: D row = kv (lg*4+r), D col = query (l15)
    f32x4 sacc[4][2] = {};
#pragma unroll
    for (int ks = 0; ks < 4; ks++)
#pragma unroll
      for (int kvb = 0; kvb < 4; kvb++) {
        bf16x8 kf = *(const bf16x8*)(sm + X * 16384 + (kvb * 4 + ks) * 1024 + lane * 16);
        sacc[kvb][0] = MFMA(kf, qf[0][ks], sacc[kvb][0]);
        sacc[kvb][1] = MFMA(kf, qf[1][ks], sacc[kvb][1]);
      }

    if (t <= 1 || t >= 8) {  // only window-edge / causal-edge tiles need masks
#pragma unroll
      for (int kvb = 0; kvb < 4; kvb++)
#pragma unroll
        for (int mb = 0; mb < 2; mb++) {
          int qg = q0 + w * 32 + mb * 16 + l15;
          int kgb = kv0 + kvb * 16 + lg * 4;
#pragma unroll
          for (int r = 0; r < 4; r++) {
            int diff = qg - (kgb + r);
            if (diff < 0 || diff > 512) sacc[kvb][mb][r] = -1e30f;
          }
        }
    }

#pragma unroll
    for (int mb = 0; mb < 2; mb++) {
      float tmax = -1e30f;
#pragma unroll
      for (int kvb = 0; kvb < 4; kvb++)
#pragma unroll
        for (int r = 0; r < 4; r++) tmax = fmaxf(tmax, sacc[kvb][mb][r]);
      tmax = fmaxf(tmax, __shfl_xor(tmax, 16));
      tmax = fmaxf(tmax, __shfl_xor(tmax, 32));
      float mnew = fmaxf(mrun[mb], tmax);
      float alpha = __expf(mrun[mb] - mnew);
      mrun[mb] = mnew;
      float lsum = 0.f;
#pragma unroll
      for (int kvb = 0; kvb < 4; kvb++) {
        u16x4 pk;
#pragma unroll
        for (int r = 0; r < 4; r++) {
          float p = __expf(sacc[kvb][mb][r] - mnew);
          lsum += p;
          pk[r] = f2bf(p);
        }
        *(u16x4*)(Ps + (mb * 16 + l15) * 144 + kvb * 32 + lg * 8) = pk;
      }
      lsum += __shfl_xor(lsum, 16);
      lsum += __shfl_xor(lsum, 32);
      lrun[mb] = lrun[mb] * alpha + lsum;
#pragma unroll
      for (int db = 0; db < 8; db++)
#pragma unroll
        for (int r = 0; r < 4; r++) oacc[db][mb][r] *= alpha;
    }

    // V(t) landed (FIFO: V(t) older than K(t+1); 8 -> 4 outstanding)
    asm volatile("s_waitcnt vmcnt(4)" ::: "memory");
    __builtin_amdgcn_s_barrier();

    // O^T += V^T · P^T  (A = V^T frag, lane-linear; B = P^T, contiguous b128)
#pragma unroll
    for (int kvs = 0; kvs < 2; kvs++) {
      bf16x8 pf0 = *(const bf16x8*)(Ps + (0 + l15) * 144 + kvs * 64 + lg * 16);
      bf16x8 pf1 = *(const bf16x8*)(Ps + (16 + l15) * 144 + kvs * 64 + lg * 16);
#pragma unroll
      for (int db = 0; db < 8; db++) {
        bf16x8 vf = *(const bf16x8*)(sm + 32768 + (db * 2 + kvs) * 1024 + lane * 16);
        oacc[db][0] = MFMA(vf, pf0, oacc[db][0]);
        oacc[db][1] = MFMA(vf, pf1, oacc[db][1]);
      }
    }
    __builtin_amdgcn_s_barrier();   // all PV reads of V done block-wide

    // stage V(t+1) -> V region
#pragma unroll
    for (int u = 0; u < 4; u++) {
      int f = w + u * 4;
      int db = f >> 1, kvs = f & 1;
      gl16(VT + (size_t)((b * 16 + h) * 128 + db * 16 + l15) * 4096 + kvn + kvs * 32 + lg * 8,
           sm + 32768 + f * 1024);
    }
    // K(t+1) landed (FIFO: K(t+1) older than V(t+1); 8 -> 4 outstanding)
    asm volatile("s_waitcnt vmcnt(4)" ::: "memory");
    __builtin_amdgcn_s_barrier();
  }

  // drain dummy tail stages before exit (next block owns this LDS)
  asm volatile("s_waitcnt vmcnt(0)" ::: "memory");

#pragma unroll
  for (int mb = 0; mb < 2; mb++) {
    float inv = 1.0f / lrun[mb];
    int s = q0 + w * 32 + mb * 16 + l15;
    unsigned short* orow = O + (size_t)(b * 4096 + s) * 2048 + h * 128 + lg * 4;
#pragma unroll
    for (int db = 0; db < 8; db++) {
      u16x4 pk;
#pragma unroll
      for (int r = 0; r < 4; r++) pk[r] = f2bf(oacc[db][mb][r] * inv);
      *(u16x4*)(orow + db * 16) = pk;
    }
  }
}

// ---------------------------------------------------------------------------
extern "C" void kernel_launch(void* const* d_in, const int* in_sizes, int n_in,
                              void* d_out, int out_size, void* d_ws, size_t ws_size,
                              hipStream_t stream) {
  const float* x = (const float*)d_in[0];       // [2,4096,2048]
  const float* w_qkv = (const float*)d_in[1];   // [6144,2048]
  const float* w_out = (const float*)d_in[2];   // [2048,2048]
  float* out = (float*)d_out;                   // [2,4096,2048] fp32

  char* ws = (char*)d_ws;
  unsigned short* XB    = (unsigned short*)(ws);                         // 32M
  unsigned short* WQKVB = (unsigned short*)(ws + 33554432);              // 24M
  unsigned short* WOUTB = (unsigned short*)(ws + 58720256);              // 8M
  unsigned short* QKb   = (unsigned short*)(ws + 67108864);              // 64M
  unsigned short* VTb   = (unsigned short*)(ws + 134217728);             // 32M
  unsigned short* OB    = XB;  // XB dead after GEMM1; reuse for attention output
  // total workspace: 160 MiB

  cast_bf16<<<16384, 256, 0, stream>>>((const float4*)x, (u16x4*)XB, 4194304);
  cast_bf16<<<12288, 256, 0, stream>>>((const float4*)w_qkv, (u16x4*)WQKVB, 3145728);
  cast_bf16<<<4096, 256, 0, stream>>>((const float4*)w_out, (u16x4*)WOUTB, 1048576);

  // qkv = x @ w_qkv^T : M=8192, N=6144, K=2048 ; 256x256 tiles, 768 blocks
  gemm_bt<1><<<768, 512, 0, stream>>>(XB, WQKVB, QKb, VTb, 2048, 0);

  // sliding-window attention: grid = B*H*(S/128)
  attn<<<1024, 256, 0, stream>>>(QKb, VTb, OB);

  // out = o @ w_out^T : M=8192, N=2048, K=2048 ; 256x256 tiles, 256 blocks
  gemm_bt<2><<<256, 512, 0, stream>>>(OB, WOUTB, out, nullptr, 2048, 2048);
}